// Round 8
// baseline (609.977 us; speedup 1.0000x reference)
//
#include <hip/hip_runtime.h>
#include <math.h>

#define N_NODES 50000
#define N_EDGES 800000
#define E_TOT   (N_EDGES + N_NODES)
#define F_IN    256
#define HEADS   8
#define OUTC    10
#define HID     80
#define NEG_SLOPE 0.2f

typedef __attribute__((ext_vector_type(8))) short bfrag;
typedef __attribute__((ext_vector_type(4))) float ffrag;

__device__ __forceinline__ unsigned short f2bf(float f) {
    unsigned u = __float_as_uint(f);
    u += 0x7FFFu + ((u >> 16) & 1u);          // RNE
    return (unsigned short)(u >> 16);
}
__device__ __forceinline__ float bf2f(unsigned short h) {
    return __uint_as_float((unsigned)h << 16);
}

// ---------------- CSR build ----------------

__global__ __launch_bounds__(256) void hist_k(const int* __restrict__ ei, int* __restrict__ cnt) {
    int e = blockIdx.x * blockDim.x + threadIdx.x;
    if (e >= E_TOT) return;
    int d = (e < N_EDGES) ? ei[N_EDGES + e] : (e - N_EDGES);
    atomicAdd(&cnt[d], 1);
}

__global__ __launch_bounds__(1024) void scan_k(const int* __restrict__ cnt, int* __restrict__ rowptr) {
    __shared__ int wsum[16];
    __shared__ int carry_s;
    const int tid = threadIdx.x;
    const int lane = tid & 63, wid = tid >> 6;
    if (tid == 0) carry_s = 0;
    __syncthreads();
    for (int base = 0; base < N_NODES; base += 1024) {
        int i = base + tid;
        int v = (i < N_NODES) ? cnt[i] : 0;
        int s = v;
        #pragma unroll
        for (int off = 1; off < 64; off <<= 1) {
            int t = __shfl_up(s, off, 64);
            if (lane >= off) s += t;
        }
        if (lane == 63) wsum[wid] = s;
        int carry = carry_s;
        __syncthreads();
        if (wid == 0 && lane < 16) {
            int w = wsum[lane];
            #pragma unroll
            for (int off = 1; off < 16; off <<= 1) {
                int t = __shfl_up(w, off, 16);
                if (lane >= off) w += t;
            }
            wsum[lane] = w;
        }
        __syncthreads();
        int woff = (wid > 0) ? wsum[wid - 1] : 0;
        int incl = s + woff;
        int excl = incl - v;
        if (i < N_NODES) rowptr[i] = carry + excl;
        int total = wsum[15];
        __syncthreads();
        if (tid == 0) carry_s = carry + total;
        __syncthreads();
    }
    if (tid == 0) rowptr[N_NODES] = carry_s;
}

__global__ __launch_bounds__(256) void scatter_k(const int* __restrict__ ei,
                                                 const int* __restrict__ rowptr,
                                                 int* __restrict__ cursor,
                                                 int* __restrict__ csr) {
    int e = blockIdx.x * blockDim.x + threadIdx.x;
    if (e >= E_TOT) return;
    int s, d;
    if (e < N_EDGES) { s = ei[e]; d = ei[N_EDGES + e]; }
    else { s = e - N_EDGES; d = s; }
    int pos = rowptr[d] + atomicAdd(&cursor[d], 1);
    csr[pos] = s;
}

// ------------- fp32 -> (bf16 hi, bf16 lo) split conversion of A -------------
// out stride Kp (>= K, zero-padded); 4 elems per thread, grid-stride.

__global__ __launch_bounds__(256) void convA_k(const float* __restrict__ in,
                                               unsigned short* __restrict__ hi,
                                               unsigned short* __restrict__ lo,
                                               int n, int K, int Kp) {
    const int cpr = Kp >> 2;
    const size_t total = (size_t)n * cpr;
    for (size_t c = (size_t)blockIdx.x * blockDim.x + threadIdx.x; c < total;
         c += (size_t)gridDim.x * blockDim.x) {
        const int row = (int)(c / cpr);
        const int k = (int)(c % cpr) << 2;
        float4 v = make_float4(0.f, 0.f, 0.f, 0.f);
        if (k < K) v = *reinterpret_cast<const float4*>(in + (size_t)row * K + k);
        unsigned short h0 = f2bf(v.x), h1 = f2bf(v.y), h2 = f2bf(v.z), h3 = f2bf(v.w);
        unsigned short l0 = f2bf(v.x - bf2f(h0)), l1 = f2bf(v.y - bf2f(h1));
        unsigned short l2 = f2bf(v.z - bf2f(h2)), l3 = f2bf(v.w - bf2f(h3));
        uint2 hp = make_uint2(((unsigned)h1 << 16) | h0, ((unsigned)h3 << 16) | h2);
        uint2 lp = make_uint2(((unsigned)l1 << 16) | l0, ((unsigned)l3 << 16) | l2);
        *reinterpret_cast<uint2*>(hi + (size_t)row * Kp + k) = hp;
        *reinterpret_cast<uint2*>(lo + (size_t)row * Kp + k) = lp;
    }
}

// ------------- W -> W^T split conversion: WT[j][k], j 0-79=Wl, 80-159=Wr ----

__global__ __launch_bounds__(256) void convW_k(const float* __restrict__ Wl,
                                               const float* __restrict__ Wr,
                                               unsigned short* __restrict__ WTh,
                                               unsigned short* __restrict__ WTl,
                                               int K, int Kp) {
    const int total = 160 * Kp;
    for (int idx = blockIdx.x * blockDim.x + threadIdx.x; idx < total;
         idx += gridDim.x * blockDim.x) {
        const int j = idx / Kp, k = idx % Kp;
        float v = 0.f;
        if (k < K) v = (j < 80) ? Wl[(size_t)k * HID + j] : Wr[(size_t)k * HID + (j - 80)];
        const unsigned short h = f2bf(v);
        WTh[idx] = h;
        WTl[idx] = f2bf(v - bf2f(h));
    }
}

// ---------------- MFMA dual GEMM (split-bf16, 3-term) ----------------
// Wave = 16 rows x 80 cols (5 col-tiles of 16). blockIdx.y: 0->Wl/xl, 1->Wr/xr.
// A-frag: lane holds A[row0+(l&15)][kb+(l>>4)*8+j]; B-frag from WT likewise.
// C: col = lane&15, row = (lane>>4)*4 + reg (m89-verified).

__global__ __launch_bounds__(256) void gemm6_k(
    const unsigned short* __restrict__ Ahi, const unsigned short* __restrict__ Alo, int Kp,
    const unsigned short* __restrict__ WTh, const unsigned short* __restrict__ WTl,
    float* __restrict__ xl, float* __restrict__ xr) {
    const int lane = threadIdx.x & 63;
    const int wv = threadIdx.x >> 6;
    const int mat = blockIdx.y;
    const int rowbase = blockIdx.x * 64 + wv * 16;
    const int m = lane & 15, kg = lane >> 4;
    const int arow = min(rowbase + m, N_NODES - 1);

    const unsigned short* __restrict__ pah = Ahi + (size_t)arow * Kp + kg * 8;
    const unsigned short* __restrict__ pal = Alo + (size_t)arow * Kp + kg * 8;
    const unsigned short* __restrict__ pbh = WTh + (size_t)(mat * 80 + m) * Kp + kg * 8;
    const unsigned short* __restrict__ pbl = WTl + (size_t)(mat * 80 + m) * Kp + kg * 8;

    ffrag acc[5];
    #pragma unroll
    for (int ct = 0; ct < 5; ++ct) acc[ct] = (ffrag){0.f, 0.f, 0.f, 0.f};

    for (int kb = 0; kb < Kp; kb += 32) {
        const bfrag ah = *reinterpret_cast<const bfrag*>(pah + kb);
        const bfrag al = *reinterpret_cast<const bfrag*>(pal + kb);
        #pragma unroll
        for (int ct = 0; ct < 5; ++ct) {
            const size_t bo = (size_t)ct * 16 * Kp + kb;
            const bfrag bh = *reinterpret_cast<const bfrag*>(pbh + bo);
            const bfrag bl = *reinterpret_cast<const bfrag*>(pbl + bo);
            acc[ct] = __builtin_amdgcn_mfma_f32_16x16x32_bf16(ah, bh, acc[ct], 0, 0, 0);
            acc[ct] = __builtin_amdgcn_mfma_f32_16x16x32_bf16(ah, bl, acc[ct], 0, 0, 0);
            acc[ct] = __builtin_amdgcn_mfma_f32_16x16x32_bf16(al, bh, acc[ct], 0, 0, 0);
        }
    }

    float* __restrict__ Xo = mat ? xr : xl;
    #pragma unroll
    for (int ct = 0; ct < 5; ++ct) {
        #pragma unroll
        for (int r = 0; r < 4; ++r) {
            const int row = rowbase + kg * 4 + r;
            if (row < N_NODES) Xo[(size_t)row * HID + ct * 16 + m] = acc[ct][r];
        }
    }
}

// ---------------- per-node online-softmax aggregation (lane = head) ----------
// lane&7 = head (lane-local logit), lane>>3 = edge slot, 3 flash merges.
// Epilogue: final layer -> fp32 d_out; else -> split-bf16 activation pair
// (rows stride 96, pad cols pre-zeroed) feeding the next MFMA GEMM.

__global__ __launch_bounds__(256) void agg2_k(const float* __restrict__ xl,
                                              const float* __restrict__ xr,
                                              const int* __restrict__ rowptr,
                                              const int* __restrict__ csr,
                                              const float* __restrict__ att,
                                              const float* __restrict__ bias,
                                              float* __restrict__ outf,
                                              unsigned short* __restrict__ outh,
                                              unsigned short* __restrict__ outl) {
    const int tid = threadIdx.x;
    const int lane = tid & 63;
    const int node = blockIdx.x * 4 + (tid >> 6);
    if (node >= N_NODES) return;
    const int eg = lane >> 3;
    const int h = lane & 7;
    const int cb = h * 10;

    float att10[10], xr10[10];
    #pragma unroll
    for (int c = 0; c < 10; ++c) {
        att10[c] = att[cb + c];
        xr10[c] = xr[(size_t)node * HID + cb + c];
    }
    const int ro = rowptr[node];
    const int deg = rowptr[node + 1] - ro;

    float m = -INFINITY, s = 0.f;
    float acc[10];
    #pragma unroll
    for (int c = 0; c < 10; ++c) acc[c] = 0.f;

    for (int i = eg; i < deg; i += 8) {
        const int src = csr[ro + i];
        const float* xlp = xl + (size_t)src * HID + cb;
        float xl10[10];
        float logit = 0.f;
        #pragma unroll
        for (int c = 0; c < 10; ++c) {
            xl10[c] = xlp[c];
            float e = xl10[c] + xr10[c];
            e = (e > 0.f) ? e : NEG_SLOPE * e;
            logit = fmaf(e, att10[c], logit);
        }
        const float nm = fmaxf(m, logit);
        const float scale = __expf(m - nm);
        const float p = __expf(logit - nm);
        s = s * scale + p;
        #pragma unroll
        for (int c = 0; c < 10; ++c) acc[c] = acc[c] * scale + p * xl10[c];
        m = nm;
    }

    #pragma unroll
    for (int off = 8; off <= 32; off <<= 1) {
        const float om = __shfl_xor(m, off, 64);
        const float os = __shfl_xor(s, off, 64);
        float oacc[10];
        #pragma unroll
        for (int c = 0; c < 10; ++c) oacc[c] = __shfl_xor(acc[c], off, 64);
        const float nm = fmaxf(m, om);
        const float sc1 = (m == -INFINITY) ? 0.f : __expf(m - nm);
        const float sc2 = (om == -INFINITY) ? 0.f : __expf(om - nm);
        s = s * sc1 + os * sc2;
        #pragma unroll
        for (int c = 0; c < 10; ++c) acc[c] = acc[c] * sc1 + oacc[c] * sc2;
        m = nm;
    }

    if (lane < 8) {
        const float inv = 1.f / (s + 1e-16f);
        #pragma unroll
        for (int c = 0; c < 10; ++c) {
            float v = acc[c] * inv + bias[cb + c];
            v = (v > 0.f) ? v : (__expf(v) - 1.f);   // ELU
            if (outf) {
                outf[(size_t)node * HID + cb + c] = v;
            } else {
                const unsigned short hh = f2bf(v);
                outh[(size_t)node * 96 + cb + c] = hh;
                outl[(size_t)node * 96 + cb + c] = f2bf(v - bf2f(hh));
            }
        }
    }
}

// ---------------- launch ----------------

extern "C" void kernel_launch(void* const* d_in, const int* in_sizes, int n_in,
                              void* d_out, int out_size, void* d_ws, size_t ws_size,
                              hipStream_t stream) {
    const float* x  = (const float*)d_in[0];
    const int*   ei = (const int*)d_in[1];
    const float* Wl[3]   = {(const float*)d_in[2], (const float*)d_in[6],  (const float*)d_in[10]};
    const float* Wr[3]   = {(const float*)d_in[3], (const float*)d_in[7],  (const float*)d_in[11]};
    const float* attp[3] = {(const float*)d_in[4], (const float*)d_in[8],  (const float*)d_in[12]};
    const float* bp[3]   = {(const float*)d_in[5], (const float*)d_in[9],  (const float*)d_in[13]};

    char* ws = (char*)d_ws;
    size_t off = 0;
    auto alloc = [&](size_t bytes) -> void* {
        void* p = ws + off;
        off += (bytes + 255) & ~(size_t)255;
        return p;
    };
    int* cnt    = (int*)alloc((size_t)N_NODES * 4);
    int* cursor = (int*)alloc((size_t)N_NODES * 4);
    int* rowptr = (int*)alloc((size_t)(N_NODES + 1) * 4);
    int* csr    = (int*)alloc((size_t)E_TOT * 4);
    float* xl   = (float*)alloc((size_t)N_NODES * HID * 4);
    float* xr   = (float*)alloc((size_t)N_NODES * HID * 4);
    unsigned short* Ahi0 = (unsigned short*)alloc((size_t)N_NODES * F_IN * 2);  // 25.6 MB
    unsigned short* Alo0 = (unsigned short*)alloc((size_t)N_NODES * F_IN * 2);
    unsigned short* WTh  = (unsigned short*)alloc((size_t)160 * F_IN * 2);
    unsigned short* WTl  = (unsigned short*)alloc((size_t)160 * F_IN * 2);
    // layer-activation split pair aliases Ahi0/Alo0 (free after layer-0 GEMM)
    unsigned short* AhiL = Ahi0;   // [N_NODES][96]
    unsigned short* AloL = Alo0;

    hipMemsetAsync(cnt, 0, (size_t)N_NODES * 4, stream);
    hipMemsetAsync(cursor, 0, (size_t)N_NODES * 4, stream);

    hist_k<<<(E_TOT + 255) / 256, 256, 0, stream>>>(ei, cnt);
    scan_k<<<1, 1024, 0, stream>>>(cnt, rowptr);
    scatter_k<<<(E_TOT + 255) / 256, 256, 0, stream>>>(ei, rowptr, cursor, csr);

    convA_k<<<4096, 256, 0, stream>>>(x, Ahi0, Alo0, N_NODES, F_IN, F_IN);

    for (int l = 0; l < 3; ++l) {
        const int K  = (l == 0) ? F_IN : HID;
        const int Kp = (l == 0) ? F_IN : 96;
        convW_k<<<64, 256, 0, stream>>>(Wl[l], Wr[l], WTh, WTl, K, Kp);
        gemm6_k<<<dim3((N_NODES + 63) / 64, 2), 256, 0, stream>>>(
            (l == 0) ? Ahi0 : AhiL, (l == 0) ? Alo0 : AloL, Kp, WTh, WTl, xl, xr);
        if (l == 0) {
            // Ahi0/Alo0 consumed; re-init as zero-padded layer-activation pair
            hipMemsetAsync(AhiL, 0, (size_t)N_NODES * 96 * 2, stream);
            hipMemsetAsync(AloL, 0, (size_t)N_NODES * 96 * 2, stream);
        }
        float* outf = (l == 2) ? (float*)d_out : nullptr;
        unsigned short* outh = (l < 2) ? AhiL : nullptr;
        unsigned short* outl = (l < 2) ? AloL : nullptr;
        agg2_k<<<N_NODES / 4, 256, 0, stream>>>(xl, xr, rowptr, csr, attp[l], bp[l],
                                                outf, outh, outl);
    }
}

// Round 9
// 586.672 us; speedup vs baseline: 1.0397x; 1.0397x over previous
//
#include <hip/hip_runtime.h>
#include <math.h>

#define N_NODES 50000
#define N_EDGES 800000
#define E_TOT   (N_EDGES + N_NODES)
#define F_IN    256
#define HEADS   8
#define OUTC    10
#define HID     80
#define NEG_SLOPE 0.2f

typedef __attribute__((ext_vector_type(8))) short bfrag;
typedef __attribute__((ext_vector_type(4))) float ffrag;

__device__ __forceinline__ unsigned short f2bf(float f) {
    unsigned u = __float_as_uint(f);
    u += 0x7FFFu + ((u >> 16) & 1u);          // RNE
    return (unsigned short)(u >> 16);
}
__device__ __forceinline__ float bf2f(unsigned short h) {
    return __uint_as_float((unsigned)h << 16);
}

// ---------------- CSR build ----------------

__global__ __launch_bounds__(256) void hist_k(const int* __restrict__ ei, int* __restrict__ cnt) {
    int e = blockIdx.x * blockDim.x + threadIdx.x;
    if (e >= E_TOT) return;
    int d = (e < N_EDGES) ? ei[N_EDGES + e] : (e - N_EDGES);
    atomicAdd(&cnt[d], 1);
}

__global__ __launch_bounds__(1024) void scan_k(const int* __restrict__ cnt, int* __restrict__ rowptr) {
    __shared__ int wsum[16];
    __shared__ int carry_s;
    const int tid = threadIdx.x;
    const int lane = tid & 63, wid = tid >> 6;
    if (tid == 0) carry_s = 0;
    __syncthreads();
    for (int base = 0; base < N_NODES; base += 1024) {
        int i = base + tid;
        int v = (i < N_NODES) ? cnt[i] : 0;
        int s = v;
        #pragma unroll
        for (int off = 1; off < 64; off <<= 1) {
            int t = __shfl_up(s, off, 64);
            if (lane >= off) s += t;
        }
        if (lane == 63) wsum[wid] = s;
        int carry = carry_s;
        __syncthreads();
        if (wid == 0 && lane < 16) {
            int w = wsum[lane];
            #pragma unroll
            for (int off = 1; off < 16; off <<= 1) {
                int t = __shfl_up(w, off, 16);
                if (lane >= off) w += t;
            }
            wsum[lane] = w;
        }
        __syncthreads();
        int woff = (wid > 0) ? wsum[wid - 1] : 0;
        int incl = s + woff;
        int excl = incl - v;
        if (i < N_NODES) rowptr[i] = carry + excl;
        int total = wsum[15];
        __syncthreads();
        if (tid == 0) carry_s = carry + total;
        __syncthreads();
    }
    if (tid == 0) rowptr[N_NODES] = carry_s;
}

__global__ __launch_bounds__(256) void scatter_k(const int* __restrict__ ei,
                                                 const int* __restrict__ rowptr,
                                                 int* __restrict__ cursor,
                                                 int* __restrict__ csr) {
    int e = blockIdx.x * blockDim.x + threadIdx.x;
    if (e >= E_TOT) return;
    int s, d;
    if (e < N_EDGES) { s = ei[e]; d = ei[N_EDGES + e]; }
    else { s = e - N_EDGES; d = s; }
    int pos = rowptr[d] + atomicAdd(&cursor[d], 1);
    csr[pos] = s;
}

// ------------- fp32 -> (bf16 hi, bf16 lo) split conversion of x -------------

__global__ __launch_bounds__(256) void convA_k(const float* __restrict__ in,
                                               unsigned short* __restrict__ hi,
                                               unsigned short* __restrict__ lo,
                                               int n, int K, int Kp) {
    const int cpr = Kp >> 2;
    const size_t total = (size_t)n * cpr;
    for (size_t c = (size_t)blockIdx.x * blockDim.x + threadIdx.x; c < total;
         c += (size_t)gridDim.x * blockDim.x) {
        const int row = (int)(c / cpr);
        const int k = (int)(c % cpr) << 2;
        float4 v = make_float4(0.f, 0.f, 0.f, 0.f);
        if (k < K) v = *reinterpret_cast<const float4*>(in + (size_t)row * K + k);
        unsigned short h0 = f2bf(v.x), h1 = f2bf(v.y), h2 = f2bf(v.z), h3 = f2bf(v.w);
        unsigned short l0 = f2bf(v.x - bf2f(h0)), l1 = f2bf(v.y - bf2f(h1));
        unsigned short l2 = f2bf(v.z - bf2f(h2)), l3 = f2bf(v.w - bf2f(h3));
        uint2 hp = make_uint2(((unsigned)h1 << 16) | h0, ((unsigned)h3 << 16) | h2);
        uint2 lp = make_uint2(((unsigned)l1 << 16) | l0, ((unsigned)l3 << 16) | l2);
        *reinterpret_cast<uint2*>(hi + (size_t)row * Kp + k) = hp;
        *reinterpret_cast<uint2*>(lo + (size_t)row * Kp + k) = lp;
    }
}

// ------------- all-layer W -> W^T split conversion (ONE dispatch) ----------
// WTh/WTl layout: L0 [160][256] at 0; L1 [160][96] at 40960; L2 at 56320.

__global__ __launch_bounds__(256) void convW3_k(
    const float* __restrict__ Wl0, const float* __restrict__ Wr0,
    const float* __restrict__ Wl1, const float* __restrict__ Wr1,
    const float* __restrict__ Wl2, const float* __restrict__ Wr2,
    unsigned short* __restrict__ WTh, unsigned short* __restrict__ WTl) {
    const int total = 160 * 256 + 2 * 160 * 96;   // 71680
    for (int idx = blockIdx.x * blockDim.x + threadIdx.x; idx < total;
         idx += gridDim.x * blockDim.x) {
        int layer, j, k, K, rem;
        if (idx < 40960)      { layer = 0; rem = idx;         j = rem / 256; k = rem % 256; K = 256; }
        else if (idx < 56320) { layer = 1; rem = idx - 40960; j = rem / 96;  k = rem % 96;  K = 80; }
        else                  { layer = 2; rem = idx - 56320; j = rem / 96;  k = rem % 96;  K = 80; }
        const float* Wl = (layer == 0) ? Wl0 : (layer == 1) ? Wl1 : Wl2;
        const float* Wr = (layer == 0) ? Wr0 : (layer == 1) ? Wr1 : Wr2;
        float v = 0.f;
        if (k < K) v = (j < 80) ? Wl[(size_t)k * HID + j] : Wr[(size_t)k * HID + (j - 80)];
        const unsigned short h = f2bf(v);
        WTh[idx] = h;
        WTl[idx] = f2bf(v - bf2f(h));
    }
}

// ---------------- MFMA dual GEMM, full A-panel preload + B dbuf ----------------
// Wave = 16 rows x 80 cols. KP compile-time; all KP/32 A-frag pairs loaded
// upfront (one latency exposure, 2*NIT concurrent loads); B (L2-hot) double-
// buffered one K-step ahead. C: col=lane&15, row=(lane>>4)*4+reg.

template<int KP>
__global__ __launch_bounds__(256) void gemm7_k(
    const unsigned short* __restrict__ Ahi, const unsigned short* __restrict__ Alo,
    const unsigned short* __restrict__ WTh, const unsigned short* __restrict__ WTl,
    float* __restrict__ xl, float* __restrict__ xr) {
    constexpr int NIT = KP / 32;
    const int lane = threadIdx.x & 63;
    const int wv = threadIdx.x >> 6;
    const int mat = blockIdx.y;
    const int rowbase = blockIdx.x * 64 + wv * 16;
    const int m = lane & 15, kg = lane >> 4;
    const int arow = min(rowbase + m, N_NODES - 1);

    const unsigned short* __restrict__ pah = Ahi + (size_t)arow * KP + kg * 8;
    const unsigned short* __restrict__ pal = Alo + (size_t)arow * KP + kg * 8;
    const unsigned short* __restrict__ pbh = WTh + (size_t)(mat * 80 + m) * KP + kg * 8;
    const unsigned short* __restrict__ pbl = WTl + (size_t)(mat * 80 + m) * KP + kg * 8;

    // full A panel preload: 2*NIT loads in flight
    bfrag ah[NIT], al[NIT];
    #pragma unroll
    for (int i = 0; i < NIT; ++i) {
        ah[i] = *reinterpret_cast<const bfrag*>(pah + i * 32);
        al[i] = *reinterpret_cast<const bfrag*>(pal + i * 32);
    }

    // B double buffer
    bfrag bh0[5], bl0[5], bh1[5], bl1[5];
    #pragma unroll
    for (int ct = 0; ct < 5; ++ct) {
        bh0[ct] = *reinterpret_cast<const bfrag*>(pbh + (size_t)ct * 16 * KP);
        bl0[ct] = *reinterpret_cast<const bfrag*>(pbl + (size_t)ct * 16 * KP);
    }

    ffrag acc[5];
    #pragma unroll
    for (int ct = 0; ct < 5; ++ct) acc[ct] = (ffrag){0.f, 0.f, 0.f, 0.f};

    #pragma unroll
    for (int i = 0; i < NIT; ++i) {
        if (i + 1 < NIT) {
            #pragma unroll
            for (int ct = 0; ct < 5; ++ct) {
                if (i & 1) {
                    bh0[ct] = *reinterpret_cast<const bfrag*>(pbh + (size_t)ct * 16 * KP + (i + 1) * 32);
                    bl0[ct] = *reinterpret_cast<const bfrag*>(pbl + (size_t)ct * 16 * KP + (i + 1) * 32);
                } else {
                    bh1[ct] = *reinterpret_cast<const bfrag*>(pbh + (size_t)ct * 16 * KP + (i + 1) * 32);
                    bl1[ct] = *reinterpret_cast<const bfrag*>(pbl + (size_t)ct * 16 * KP + (i + 1) * 32);
                }
            }
        }
        #pragma unroll
        for (int ct = 0; ct < 5; ++ct) {
            const bfrag bh = (i & 1) ? bh1[ct] : bh0[ct];
            const bfrag bl = (i & 1) ? bl1[ct] : bl0[ct];
            acc[ct] = __builtin_amdgcn_mfma_f32_16x16x32_bf16(ah[i], bh, acc[ct], 0, 0, 0);
            acc[ct] = __builtin_amdgcn_mfma_f32_16x16x32_bf16(ah[i], bl, acc[ct], 0, 0, 0);
            acc[ct] = __builtin_amdgcn_mfma_f32_16x16x32_bf16(al[i], bh, acc[ct], 0, 0, 0);
        }
    }

    float* __restrict__ Xo = mat ? xr : xl;
    #pragma unroll
    for (int ct = 0; ct < 5; ++ct) {
        #pragma unroll
        for (int r = 0; r < 4; ++r) {
            const int row = rowbase + kg * 4 + r;
            if (row < N_NODES) Xo[(size_t)row * HID + ct * 16 + m] = acc[ct][r];
        }
    }
}

// ---------------- per-node online-softmax aggregation (lane = head) ----------
// lane&7 = head, lane>>3 = edge slot, 3 flash merges. Final layer -> fp32
// d_out; else -> split-bf16 pair stride 96 (lanes 8-15 zero the K-pad).

__global__ __launch_bounds__(256) void agg2_k(const float* __restrict__ xl,
                                              const float* __restrict__ xr,
                                              const int* __restrict__ rowptr,
                                              const int* __restrict__ csr,
                                              const float* __restrict__ att,
                                              const float* __restrict__ bias,
                                              float* __restrict__ outf,
                                              unsigned short* __restrict__ outh,
                                              unsigned short* __restrict__ outl) {
    const int tid = threadIdx.x;
    const int lane = tid & 63;
    const int node = blockIdx.x * 4 + (tid >> 6);
    if (node >= N_NODES) return;
    const int eg = lane >> 3;
    const int h = lane & 7;
    const int cb = h * 10;

    float att10[10], xr10[10];
    #pragma unroll
    for (int c = 0; c < 10; ++c) {
        att10[c] = att[cb + c];
        xr10[c] = xr[(size_t)node * HID + cb + c];
    }
    const int ro = rowptr[node];
    const int deg = rowptr[node + 1] - ro;

    float m = -INFINITY, s = 0.f;
    float acc[10];
    #pragma unroll
    for (int c = 0; c < 10; ++c) acc[c] = 0.f;

    for (int i = eg; i < deg; i += 8) {
        const int src = csr[ro + i];
        const float* xlp = xl + (size_t)src * HID + cb;
        float xl10[10];
        float logit = 0.f;
        #pragma unroll
        for (int c = 0; c < 10; ++c) {
            xl10[c] = xlp[c];
            float e = xl10[c] + xr10[c];
            e = (e > 0.f) ? e : NEG_SLOPE * e;
            logit = fmaf(e, att10[c], logit);
        }
        const float nm = fmaxf(m, logit);
        const float scale = __expf(m - nm);
        const float p = __expf(logit - nm);
        s = s * scale + p;
        #pragma unroll
        for (int c = 0; c < 10; ++c) acc[c] = acc[c] * scale + p * xl10[c];
        m = nm;
    }

    #pragma unroll
    for (int off = 8; off <= 32; off <<= 1) {
        const float om = __shfl_xor(m, off, 64);
        const float os = __shfl_xor(s, off, 64);
        float oacc[10];
        #pragma unroll
        for (int c = 0; c < 10; ++c) oacc[c] = __shfl_xor(acc[c], off, 64);
        const float nm = fmaxf(m, om);
        const float sc1 = (m == -INFINITY) ? 0.f : __expf(m - nm);
        const float sc2 = (om == -INFINITY) ? 0.f : __expf(om - nm);
        s = s * sc1 + os * sc2;
        #pragma unroll
        for (int c = 0; c < 10; ++c) acc[c] = acc[c] * sc1 + oacc[c] * sc2;
        m = nm;
    }

    if (lane < 8) {
        const float inv = 1.f / (s + 1e-16f);
        #pragma unroll
        for (int c = 0; c < 10; ++c) {
            float v = acc[c] * inv + bias[cb + c];
            v = (v > 0.f) ? v : (__expf(v) - 1.f);   // ELU
            if (outf) {
                outf[(size_t)node * HID + cb + c] = v;
            } else {
                const unsigned short hh = f2bf(v);
                outh[(size_t)node * 96 + cb + c] = hh;
                outl[(size_t)node * 96 + cb + c] = f2bf(v - bf2f(hh));
            }
        }
    } else if (lane < 16 && outh) {
        const int c0 = 80 + (lane - 8) * 2;          // zero the K-pad cols 80..95
        outh[(size_t)node * 96 + c0] = 0; outh[(size_t)node * 96 + c0 + 1] = 0;
        outl[(size_t)node * 96 + c0] = 0; outl[(size_t)node * 96 + c0 + 1] = 0;
    }
}

// ---------------- launch ----------------

extern "C" void kernel_launch(void* const* d_in, const int* in_sizes, int n_in,
                              void* d_out, int out_size, void* d_ws, size_t ws_size,
                              hipStream_t stream) {
    const float* x  = (const float*)d_in[0];
    const int*   ei = (const int*)d_in[1];
    const float* Wl[3]   = {(const float*)d_in[2], (const float*)d_in[6],  (const float*)d_in[10]};
    const float* Wr[3]   = {(const float*)d_in[3], (const float*)d_in[7],  (const float*)d_in[11]};
    const float* attp[3] = {(const float*)d_in[4], (const float*)d_in[8],  (const float*)d_in[12]};
    const float* bp[3]   = {(const float*)d_in[5], (const float*)d_in[9],  (const float*)d_in[13]};

    char* ws = (char*)d_ws;
    size_t off = 0;
    auto alloc = [&](size_t bytes) -> void* {
        void* p = ws + off;
        off += (bytes + 255) & ~(size_t)255;
        return p;
    };
    int* cnt    = (int*)alloc((size_t)N_NODES * 4);
    int* cursor = (int*)alloc((size_t)N_NODES * 4);
    int* rowptr = (int*)alloc((size_t)(N_NODES + 1) * 4);
    int* csr    = (int*)alloc((size_t)E_TOT * 4);
    float* xl   = (float*)alloc((size_t)N_NODES * HID * 4);
    float* xr   = (float*)alloc((size_t)N_NODES * HID * 4);
    unsigned short* Ahi0 = (unsigned short*)alloc((size_t)N_NODES * F_IN * 2);
    unsigned short* Alo0 = (unsigned short*)alloc((size_t)N_NODES * F_IN * 2);
    unsigned short* AhiL = (unsigned short*)alloc((size_t)N_NODES * 96 * 2);
    unsigned short* AloL = (unsigned short*)alloc((size_t)N_NODES * 96 * 2);
    unsigned short* WTh  = (unsigned short*)alloc((size_t)71680 * 2);
    unsigned short* WTl  = (unsigned short*)alloc((size_t)71680 * 2);

    hipMemsetAsync(cnt, 0, (size_t)N_NODES * 4, stream);
    hipMemsetAsync(cursor, 0, (size_t)N_NODES * 4, stream);

    hist_k<<<(E_TOT + 255) / 256, 256, 0, stream>>>(ei, cnt);
    scan_k<<<1, 1024, 0, stream>>>(cnt, rowptr);
    scatter_k<<<(E_TOT + 255) / 256, 256, 0, stream>>>(ei, rowptr, cursor, csr);

    convA_k<<<4096, 256, 0, stream>>>(x, Ahi0, Alo0, N_NODES, F_IN, F_IN);
    convW3_k<<<280, 256, 0, stream>>>(Wl[0], Wr[0], Wl[1], Wr[1], Wl[2], Wr[2], WTh, WTl);

    const unsigned short* WThL[3] = {WTh, WTh + 40960, WTh + 56320};
    const unsigned short* WTlL[3] = {WTl, WTl + 40960, WTl + 56320};

    for (int l = 0; l < 3; ++l) {
        if (l == 0)
            gemm7_k<256><<<dim3((N_NODES + 63) / 64, 2), 256, 0, stream>>>(
                Ahi0, Alo0, WThL[l], WTlL[l], xl, xr);
        else
            gemm7_k<96><<<dim3((N_NODES + 63) / 64, 2), 256, 0, stream>>>(
                AhiL, AloL, WThL[l], WTlL[l], xl, xr);
        float* outf = (l == 2) ? (float*)d_out : nullptr;
        unsigned short* outh = (l < 2) ? AhiL : nullptr;
        unsigned short* outl = (l < 2) ? AloL : nullptr;
        agg2_k<<<N_NODES / 4, 256, 0, stream>>>(xl, xr, rowptr, csr, attp[l], bp[l],
                                                outf, outh, outl);
    }
}